// Round 2
// baseline (1096.649 us; speedup 1.0000x reference)
//
#include <hip/hip_runtime.h>
#include <math.h>

#define BB 64
#define NN 4096
#define FF 128
#define KK 64
#define TILE 128
#define NSTEP 4
#define SPB 32      // stats partial blocks per batch

__device__ __forceinline__ float dot4acc(float4 a, float4 b, float s) {
    return fmaf(a.w, b.w, fmaf(a.z, b.z, fmaf(a.y, b.y, fmaf(a.x, b.x, s))));
}

// ---------- stats: partial sums of emb and emb^2 over n (masked) ----------
__global__ void k_stats_part(const float* __restrict__ emb, const int* __restrict__ nbv,
                             float* __restrict__ spart) {
    int b = blockIdx.y, s = blockIdx.x;
    int nb = nbv[b];
    int t = threadIdx.x;                 // 256
    int c = t & 31, rr = t >> 5;
    int n0 = s * (NN / SPB);             // 128 rows per block
    int n1 = min(n0 + NN / SPB, nb);
    float4 s1 = {0,0,0,0}, s2 = {0,0,0,0};
    const float4* base = (const float4*)(emb + (size_t)b * NN * FF);
    for (int n = n0 + rr; n < n1; n += 8) {
        float4 e = base[(size_t)n * 32 + c];
        s1.x += e.x; s1.y += e.y; s1.z += e.z; s1.w += e.w;
        s2.x += e.x*e.x; s2.y += e.y*e.y; s2.z += e.z*e.z; s2.w += e.w*e.w;
    }
    __shared__ __align__(16) float4 r1[8][32];
    __shared__ __align__(16) float4 r2[8][32];
    r1[rr][c] = s1; r2[rr][c] = s2;
    __syncthreads();
    if (t < 32) {
        float4 a1 = r1[0][t], a2 = r2[0][t];
        #pragma unroll
        for (int r = 1; r < 8; ++r) {
            float4 u = r1[r][t], v = r2[r][t];
            a1.x+=u.x; a1.y+=u.y; a1.z+=u.z; a1.w+=u.w;
            a2.x+=v.x; a2.y+=v.y; a2.z+=v.z; a2.w+=v.w;
        }
        ((float4*)(spart + ((size_t)(b*SPB+s)*2 + 0)*FF))[t] = a1;
        ((float4*)(spart + ((size_t)(b*SPB+s)*2 + 1)*FF))[t] = a2;
    }
}

// ---------- stats finalize ----------
__global__ void k_stats_fin(const float* __restrict__ spart, const int* __restrict__ nbv,
                            float* __restrict__ meanp, float* __restrict__ rstdp) {
    int b = blockIdx.x, f = threadIdx.x;   // 128 threads
    float s1 = 0.f, s2 = 0.f;
    for (int s = 0; s < SPB; ++s) {
        s1 += spart[((size_t)(b*SPB+s)*2 + 0)*FF + f];
        s2 += spart[((size_t)(b*SPB+s)*2 + 1)*FF + f];
    }
    float nb = (float)nbv[b];
    float mean = s1 / nb;
    float var = s2 / nb - mean * mean;
    meanp[b*FF + f] = mean;
    rstdp[b*FF + f] = rsqrtf(var + 1e-5f);
}

// ---------- init mu = x[:, init_idx] ----------
__global__ void k_init(const float* __restrict__ emb, const int* __restrict__ nbv,
                       const int* __restrict__ init_idx,
                       const float* __restrict__ meanp, const float* __restrict__ rstdp,
                       float* __restrict__ mu) {
    size_t i = (size_t)blockIdx.x * 256 + threadIdx.x;   // < B*K*F
    int f = (int)(i & 127);
    int k = (int)((i >> 7) & 63);
    int b = (int)(i >> 13);
    int row = init_idx[k];
    float v = 0.f;
    if (row < nbv[b]) {
        float e = emb[((size_t)b * NN + row) * FF + f];
        v = (e - meanp[b*FF + f]) * rstdp[b*FF + f];
    }
    mu[i] = v;
}

// ---------- zero a float buffer (f4 granular) ----------
__global__ void k_zero(float* __restrict__ p) {
    size_t i = (size_t)blockIdx.x * 1024 + threadIdx.x;
    ((float4*)p)[i] = make_float4(0.f, 0.f, 0.f, 0.f);
}

// ---------- EM step, one 128-row tile per block ----------
__global__ __launch_bounds__(1024, 4) void k_em2(const float* __restrict__ emb,
                                                 const int* __restrict__ nbv,
                                                 const float* __restrict__ meanp,
                                                 const float* __restrict__ rstdp,
                                                 const float* __restrict__ mu_in,
                                                 float* __restrict__ mu_out) {
    __shared__ __align__(16) float4 xs[TILE][32];   // x tile, slot ^= (r>>2)&7
    __shared__ __align__(16) float4 mus[KK][32];    // mu,     slot ^= (r>>2)&7
    __shared__ __align__(16) float sp[TILE][64];    // S/P, f4-slot ^= (r>>2)&7
    __shared__ float x2s[TILE];
    __shared__ float m2s[KK];

    int b = blockIdx.y, tt = blockIdx.x;
    int nb = nbv[b];
    int row0 = tt * TILE;
    if (row0 >= nb) return;                 // load-balanced early exit
    int t = threadIdx.x;                    // 1024
    int lane = t & 63, w = t >> 6;          // 16 waves

    // stage mu + |mu|^2 per row
    {
        const float4* src = (const float4*)(mu_in + (size_t)b * KK * FF);
        #pragma unroll
        for (int j = 0; j < 2; ++j) {
            int g = t + 1024 * j;           // 2048 float4s
            int r = g >> 5, c = g & 31;
            float4 v = src[g];
            mus[r][c ^ ((r >> 2) & 7)] = v;
            float q = v.x*v.x + v.y*v.y + v.z*v.z + v.w*v.w;
            q += __shfl_xor(q, 16); q += __shfl_xor(q, 8);
            q += __shfl_xor(q, 4);  q += __shfl_xor(q, 2); q += __shfl_xor(q, 1);
            if ((t & 31) == 0) m2s[r] = q;
        }
    }

    // stage x tile (normalize on the fly) + |x|^2 per row
    {
        const float4* erow = (const float4*)(emb + ((size_t)b * NN + row0) * FF);
        int c = t & 31;                     // constant across j (1024 % 32 == 0)
        float4 mn = ((const float4*)(meanp + b * FF))[c];
        float4 rs = ((const float4*)(rstdp + b * FF))[c];
        #pragma unroll
        for (int j = 0; j < 4; ++j) {
            int g = t + 1024 * j;           // 4096 float4s
            int r = g >> 5;
            int n = row0 + r;
            float4 v = {0,0,0,0};
            if (n < nb) {
                float4 e = erow[g];
                v.x = (e.x - mn.x) * rs.x;
                v.y = (e.y - mn.y) * rs.y;
                v.z = (e.z - mn.z) * rs.z;
                v.w = (e.w - mn.w) * rs.w;
            }
            xs[r][c ^ ((r >> 2) & 7)] = v;
            float q = v.x*v.x + v.y*v.y + v.z*v.z + v.w*v.w;
            q += __shfl_xor(q, 16); q += __shfl_xor(q, 8);
            q += __shfl_xor(q, 4);  q += __shfl_xor(q, 2); q += __shfl_xor(q, 1);
            if ((t & 31) == 0) x2s[r] = q;
        }
    }
    __syncthreads();

    // ---- GEMM1: S[128][64] = x . mu^T ; per-lane 2 rows x 4 ks ----
    {
        int wr = w & 7, wk = w >> 3;            // 8 row-groups x 2 k-groups
        int lr = lane & 7, lk = lane >> 3;
        int r0 = wr * 16 + lr * 2;
        int k4 = wk * 8 + lk;                   // float4-slot of k
        int aswz = (r0 >> 2) & 7;               // same for r0, r0+1
        int bswz = k4 & 7;
        float4 s0 = {0,0,0,0}, s1 = {0,0,0,0};
        #pragma unroll 2
        for (int fc = 0; fc < 32; ++fc) {
            int as = fc ^ aswz, bs = fc ^ bswz;
            float4 a0 = xs[r0 + 0][as];
            float4 a1 = xs[r0 + 1][as];
            float4 b0 = mus[k4*4 + 0][bs];
            float4 b1 = mus[k4*4 + 1][bs];
            float4 b2 = mus[k4*4 + 2][bs];
            float4 b3 = mus[k4*4 + 3][bs];
            s0.x = dot4acc(a0, b0, s0.x); s0.y = dot4acc(a0, b1, s0.y);
            s0.z = dot4acc(a0, b2, s0.z); s0.w = dot4acc(a0, b3, s0.w);
            s1.x = dot4acc(a1, b0, s1.x); s1.y = dot4acc(a1, b1, s1.y);
            s1.z = dot4acc(a1, b2, s1.z); s1.w = dot4acc(a1, b3, s1.w);
        }
        ((float4*)&sp[r0 + 0][0])[k4 ^ aswz] = s0;
        ((float4*)&sp[r0 + 1][0])[k4 ^ aswz] = s1;
    }
    __syncthreads();

    // ---- P = (exp(-.5*norm)+1e-20)/(rowsum+1e-40); 16 waves x 8 rows ----
    #pragma unroll
    for (int i = 0; i < 8; ++i) {
        int r = w * 8 + i;
        int swz = (r >> 2) & 7;
        int col = (((lane >> 2) ^ swz) << 2) | (lane & 3);
        float s = sp[r][col];
        float norm = x2s[r] - 2.f * s + m2s[lane];
        float lik = expf(-0.5f * norm) + 1e-20f;
        float tot = lik;
        tot += __shfl_xor(tot, 1);  tot += __shfl_xor(tot, 2);
        tot += __shfl_xor(tot, 4);  tot += __shfl_xor(tot, 8);
        tot += __shfl_xor(tot, 16); tot += __shfl_xor(tot, 32);
        sp[r][col] = lik / (tot + 1e-40f);
    }
    __syncthreads();

    // ---- GEMM2: mu_out[64][128] += P^T . x ; per-lane 2 ks x 4 fs ----
    {
        int wf = w & 3, wk2 = w >> 2;           // 4 f-groups x 4 k-groups
        int lk = lane & 7, lf = lane >> 3;
        int k0 = wk2 * 16 + lk * 2;
        int fslot = wf * 8 + lf;
        float4 a0 = {0,0,0,0}, a1 = {0,0,0,0};
        #pragma unroll 4
        for (int n = 0; n < TILE; ++n) {
            int swz = (n >> 2) & 7;
            float2 p = *(const float2*)&sp[n][((((k0 >> 2) ^ swz)) << 2) | (k0 & 3)];
            float4 x4 = xs[n][fslot ^ swz];
            a0.x = fmaf(p.x, x4.x, a0.x); a0.y = fmaf(p.x, x4.y, a0.y);
            a0.z = fmaf(p.x, x4.z, a0.z); a0.w = fmaf(p.x, x4.w, a0.w);
            a1.x = fmaf(p.y, x4.x, a1.x); a1.y = fmaf(p.y, x4.y, a1.y);
            a1.z = fmaf(p.y, x4.z, a1.z); a1.w = fmaf(p.y, x4.w, a1.w);
        }
        float* d0 = mu_out + ((size_t)b * KK + k0) * FF + fslot * 4;
        unsafeAtomicAdd(d0 + 0, a0.x); unsafeAtomicAdd(d0 + 1, a0.y);
        unsafeAtomicAdd(d0 + 2, a0.z); unsafeAtomicAdd(d0 + 3, a0.w);
        float* d1 = d0 + FF;
        unsafeAtomicAdd(d1 + 0, a1.x); unsafeAtomicAdd(d1 + 1, a1.y);
        unsafeAtomicAdd(d1 + 2, a1.z); unsafeAtomicAdd(d1 + 3, a1.w);
    }
}

// ---------- final: out[b] = sigmoid(mean_k(mu . w) + bias) ----------
__global__ void k_final(const float* __restrict__ mu, const float* __restrict__ fc_w,
                        const float* __restrict__ fc_b, float* __restrict__ out) {
    int b = blockIdx.x, t = threadIdx.x;     // 256 threads
    int k = t >> 2, q = t & 3;
    const float* m = mu + ((size_t)b * KK + k) * FF + q * 32;
    const float* wv = fc_w + q * 32;
    float s = 0.f;
    #pragma unroll
    for (int i = 0; i < 32; ++i) s = fmaf(m[i], wv[i], s);
    s += __shfl_xor(s, 1); s += __shfl_xor(s, 2);
    __shared__ float kd[KK];
    if (q == 0) kd[k] = s;
    __syncthreads();
    if (t < 64) {
        float v = kd[t];
        v += __shfl_xor(v, 1);  v += __shfl_xor(v, 2);  v += __shfl_xor(v, 4);
        v += __shfl_xor(v, 8);  v += __shfl_xor(v, 16); v += __shfl_xor(v, 32);
        if (t == 0) {
            float o = v / (float)KK + fc_b[0];
            out[b] = 1.f / (1.f + expf(-o));
        }
    }
}

extern "C" void kernel_launch(void* const* d_in, const int* in_sizes, int n_in,
                              void* d_out, int out_size, void* d_ws, size_t ws_size,
                              hipStream_t stream) {
    const float* emb      = (const float*)d_in[0];
    // d_in[1] = mask — redundant with batch_nb_nodes; unused
    const float* fc_w     = (const float*)d_in[2];
    const float* fc_b     = (const float*)d_in[3];
    const int*   nbv      = (const int*)d_in[4];
    const int*   init_idx = (const int*)d_in[5];
    float* out = (float*)d_out;

    float* wsf   = (float*)d_ws;
    float* meanp = wsf;                          // B*F
    float* rstdp = meanp + BB*FF;                // B*F
    float* spart = rstdp + BB*FF;                // B*SPB*2*F
    float* muA   = spart + (size_t)BB*SPB*2*FF;  // B*K*F
    float* muB   = muA + (size_t)BB*KK*FF;       // B*K*F

    k_stats_part<<<dim3(SPB, BB), 256, 0, stream>>>(emb, nbv, spart);
    k_stats_fin<<<BB, 128, 0, stream>>>(spart, nbv, meanp, rstdp);
    k_init<<<(BB*KK*FF)/256, 256, 0, stream>>>(emb, nbv, init_idx, meanp, rstdp, muA);

    const int zblocks = (BB*KK*FF/4) / 1024;     // 128
    for (int step = 0; step < NSTEP; ++step) {
        const float* mu_in = (step & 1) ? muB : muA;
        float* mu_out      = (step & 1) ? muA : muB;
        k_zero<<<zblocks, 1024, 0, stream>>>(mu_out);
        k_em2<<<dim3(NN/TILE, BB), 1024, 0, stream>>>(emb, nbv, meanp, rstdp, mu_in, mu_out);
    }
    // after step 3, result is in muA
    k_final<<<BB, 256, 0, stream>>>(muA, fc_w, fc_b, out);
}

// Round 3
// 778.691 us; speedup vs baseline: 1.4083x; 1.4083x over previous
//
#include <hip/hip_runtime.h>
#include <math.h>

#define BB 64
#define NN 4096
#define FF 128
#define KK 64
#define TILE 128
#define NSTEP 4
#define SPB 32

typedef short bf16x8 __attribute__((ext_vector_type(8)));
typedef float f32x4 __attribute__((ext_vector_type(4)));

__device__ __forceinline__ ushort f2bf(float f) {
    union { float f; unsigned u; } c; c.f = f;
    unsigned r = c.u + 0x7FFFu + ((c.u >> 16) & 1u);
    return (ushort)(r >> 16);
}
__device__ __forceinline__ float bf2f(ushort h) {
    union { unsigned u; float f; } c; c.u = ((unsigned)h) << 16;
    return c.f;
}

// ---------- stats: partial sums of emb and emb^2 over n (masked) ----------
__global__ void k_stats_part(const float* __restrict__ emb, const int* __restrict__ nbv,
                             float* __restrict__ spart) {
    int b = blockIdx.y, s = blockIdx.x;
    int nb = nbv[b];
    int t = threadIdx.x;                 // 256
    int c = t & 31, rr = t >> 5;
    int n0 = s * (NN / SPB);
    int n1 = min(n0 + NN / SPB, nb);
    float4 s1 = {0,0,0,0}, s2 = {0,0,0,0};
    const float4* base = (const float4*)(emb + (size_t)b * NN * FF);
    for (int n = n0 + rr; n < n1; n += 8) {
        float4 e = base[(size_t)n * 32 + c];
        s1.x += e.x; s1.y += e.y; s1.z += e.z; s1.w += e.w;
        s2.x += e.x*e.x; s2.y += e.y*e.y; s2.z += e.z*e.z; s2.w += e.w*e.w;
    }
    __shared__ __align__(16) float4 r1[8][32];
    __shared__ __align__(16) float4 r2[8][32];
    r1[rr][c] = s1; r2[rr][c] = s2;
    __syncthreads();
    if (t < 32) {
        float4 a1 = r1[0][t], a2 = r2[0][t];
        #pragma unroll
        for (int r = 1; r < 8; ++r) {
            float4 u = r1[r][t], v = r2[r][t];
            a1.x+=u.x; a1.y+=u.y; a1.z+=u.z; a1.w+=u.w;
            a2.x+=v.x; a2.y+=v.y; a2.z+=v.z; a2.w+=v.w;
        }
        ((float4*)(spart + ((size_t)(b*SPB+s)*2 + 0)*FF))[t] = a1;
        ((float4*)(spart + ((size_t)(b*SPB+s)*2 + 1)*FF))[t] = a2;
    }
}

// ---------- stats finalize ----------
__global__ void k_stats_fin(const float* __restrict__ spart, const int* __restrict__ nbv,
                            float* __restrict__ meanp, float* __restrict__ rstdp) {
    int b = blockIdx.x, f = threadIdx.x;   // 128 threads
    float s1 = 0.f, s2 = 0.f;
    for (int s = 0; s < SPB; ++s) {
        s1 += spart[((size_t)(b*SPB+s)*2 + 0)*FF + f];
        s2 += spart[((size_t)(b*SPB+s)*2 + 1)*FF + f];
    }
    float nb = (float)nbv[b];
    float mean = s1 / nb;
    float var = s2 / nb - mean * mean;
    meanp[b*FF + f] = mean;
    rstdp[b*FF + f] = rsqrtf(var + 1e-5f);
}

// ---------- init mu = x[:, init_idx] (f32) ----------
__global__ void k_init(const float* __restrict__ emb, const int* __restrict__ nbv,
                       const int* __restrict__ init_idx,
                       const float* __restrict__ meanp, const float* __restrict__ rstdp,
                       float* __restrict__ mu) {
    size_t i = (size_t)blockIdx.x * 256 + threadIdx.x;   // < B*K*F
    int f = (int)(i & 127);
    int k = (int)((i >> 7) & 63);
    int b = (int)(i >> 13);
    int row = init_idx[k];
    float v = 0.f;
    if (row < nbv[b]) {
        float e = emb[((size_t)b * NN + row) * FF + f];
        v = (e - meanp[b*FF + f]) * rstdp[b*FF + f];
    }
    mu[i] = v;
}

// ---------- split mu f32 -> bf16 hi/lo + |mu|^2 ----------
__global__ void k_split(const float* __restrict__ mu, ushort* __restrict__ muh,
                        ushort* __restrict__ mul, float* __restrict__ m2g) {
    int b = blockIdx.x, t = threadIdx.x;   // 256 threads
    int k = t >> 2, q = t & 3;
    size_t base = ((size_t)b * KK + k) * FF + q * 32;
    float m2 = 0.f;
    #pragma unroll
    for (int it = 0; it < 8; ++it) {
        float4 v = *(const float4*)(mu + base + it*4);
        m2 += v.x*v.x + v.y*v.y + v.z*v.z + v.w*v.w;
        ushort4 h4, l4;
        h4.x = f2bf(v.x); l4.x = f2bf(v.x - bf2f(h4.x));
        h4.y = f2bf(v.y); l4.y = f2bf(v.y - bf2f(h4.y));
        h4.z = f2bf(v.z); l4.z = f2bf(v.z - bf2f(h4.z));
        h4.w = f2bf(v.w); l4.w = f2bf(v.w - bf2f(h4.w));
        *(ushort4*)(muh + base + it*4) = h4;
        *(ushort4*)(mul + base + it*4) = l4;
    }
    m2 += __shfl_xor(m2, 1); m2 += __shfl_xor(m2, 2);
    if (q == 0) m2g[b*KK + k] = m2;
}

// ---------- zero f32 buffer ----------
__global__ void k_zero(float* __restrict__ p) {
    size_t i = (size_t)blockIdx.x * 256 + threadIdx.x;
    ((float4*)p)[i] = make_float4(0.f, 0.f, 0.f, 0.f);
}

// ---------- EM step: MFMA split-bf16, one 128-row tile per block ----------
// LDS 64 KB static: xT (f-major half-tile, hi/lo) + pT (P transposed, hi/lo).
__global__ __launch_bounds__(1024, 4) void k_em3(const float* __restrict__ emb,
                                                 const int* __restrict__ nbv,
                                                 const float* __restrict__ meanp,
                                                 const float* __restrict__ rstdp,
                                                 const ushort* __restrict__ muh,
                                                 const ushort* __restrict__ mul,
                                                 const float* __restrict__ m2g,
                                                 float* __restrict__ mu_out) {
    __shared__ __align__(16) ushort xTh[FF * 64];   // 16 KB  [f][64 n-half], granule^=(f&7)
    __shared__ __align__(16) ushort xTl[FF * 64];   // 16 KB
    __shared__ __align__(16) ushort pTh[KK * TILE]; // 16 KB  [k][128 n], granule^=(k&7)
    __shared__ __align__(16) ushort pTl[KK * TILE]; // 16 KB

    int bb = blockIdx.y, tt = blockIdx.x;
    int nb = nbv[bb];
    int row0 = tt * TILE;
    if (row0 >= nb) return;
    int t = threadIdx.x;                  // 1024
    int lane = t & 63, w = t >> 6;        // 16 waves
    int b = lane & 15, g = lane >> 4;

    const float* mnB = meanp + bb * FF;
    const float* rsB = rstdp + bb * FF;

    f32x4 acc1[4];                        // GEMM1: S[n=16w+4g+j][k=16kt+b]
    float a2 = 0.f;                       // |x|^2 of row 16w+b

    if (w < 8) {
        // ===== GEMM1: S = x . mu^T ; A from emb (normalize+split on the fly), B from global mu =====
        #pragma unroll
        for (int kt = 0; kt < 4; ++kt) acc1[kt] = (f32x4){0.f,0.f,0.f,0.f};
        int nA = row0 + 16*w + b;
        const float* erow = emb + ((size_t)bb * NN + nA) * FF;
        const ushort* muhB = muh + (size_t)bb * KK * FF;
        const ushort* mulB = mul + (size_t)bb * KK * FF;
        #pragma unroll
        for (int kk = 0; kk < 4; ++kk) {
            int f0 = kk*32 + g*8;
            float4 e0 = *(const float4*)(erow + f0);
            float4 e1 = *(const float4*)(erow + f0 + 4);
            float4 m0 = *(const float4*)(mnB + f0);
            float4 m1 = *(const float4*)(mnB + f0 + 4);
            float4 r0 = *(const float4*)(rsB + f0);
            float4 r1 = *(const float4*)(rsB + f0 + 4);
            float vv[8];
            vv[0] = (e0.x - m0.x)*r0.x; vv[1] = (e0.y - m0.y)*r0.y;
            vv[2] = (e0.z - m0.z)*r0.z; vv[3] = (e0.w - m0.w)*r0.w;
            vv[4] = (e1.x - m1.x)*r1.x; vv[5] = (e1.y - m1.y)*r1.y;
            vv[6] = (e1.z - m1.z)*r1.z; vv[7] = (e1.w - m1.w)*r1.w;
            bf16x8 ah, al;
            #pragma unroll
            for (int i = 0; i < 8; ++i) {
                a2 += vv[i]*vv[i];
                ushort h = f2bf(vv[i]);
                ah[i] = (short)h;
                al[i] = (short)f2bf(vv[i] - bf2f(h));
            }
            #pragma unroll
            for (int kt = 0; kt < 4; ++kt) {
                size_t mo = (size_t)(kt*16 + b) * FF + f0;
                bf16x8 Bh = *(const bf16x8*)(muhB + mo);
                bf16x8 Bl = *(const bf16x8*)(mulB + mo);
                acc1[kt] = __builtin_amdgcn_mfma_f32_16x16x32_bf16(ah, Bh, acc1[kt], 0, 0, 0);
                acc1[kt] = __builtin_amdgcn_mfma_f32_16x16x32_bf16(ah, Bl, acc1[kt], 0, 0, 0);
                acc1[kt] = __builtin_amdgcn_mfma_f32_16x16x32_bf16(al, Bh, acc1[kt], 0, 0, 0);
            }
        }
        a2 += __shfl_xor(a2, 16);
        a2 += __shfl_xor(a2, 32);         // all lanes: x2 of row 16w + (lane&15)
    } else {
        // ===== build xT half 1 (tile rows 0..63), f-major, zero-padded past nb =====
        int t2 = t - 512;                 // 0..511
        int nl = t2 & 63;                 // n local (= tile row)
        int fq = t2 >> 6;                 // 0..7
        int gn = row0 + nl;
        bool valid = gn < nb;
        const float* er = emb + ((size_t)bb * NN + gn) * FF;
        #pragma unroll
        for (int it = 0; it < 4; ++it) {
            int f4 = fq + 8*it;           // f = 4*f4 .. +3
            float4 e = valid ? *(const float4*)(er + 4*f4) : make_float4(0.f,0.f,0.f,0.f);
            float4 mn = *(const float4*)(mnB + 4*f4);
            float4 rs = *(const float4*)(rsB + 4*f4);
            float vx[4];
            vx[0] = valid ? (e.x - mn.x)*rs.x : 0.f;
            vx[1] = valid ? (e.y - mn.y)*rs.y : 0.f;
            vx[2] = valid ? (e.z - mn.z)*rs.z : 0.f;
            vx[3] = valid ? (e.w - mn.w)*rs.w : 0.f;
            #pragma unroll
            for (int ei = 0; ei < 4; ++ei) {
                int f = 4*f4 + ei;
                ushort h = f2bf(vx[ei]);
                ushort l = f2bf(vx[ei] - bf2f(h));
                int idx = f*64 + ((((nl>>3) ^ (f&7)) << 3) | (nl & 7));
                xTh[idx] = h;
                xTl[idx] = l;
            }
        }
    }
    __syncthreads();   // bar1: xT half1 + GEMM1 regs ready

    if (w < 8) {
        // ===== softmax rows: P = (exp(-.5*(x2 - 2S + m2)) + 1e-20) / (rowsum + 1e-40) =====
        float x2v[4], m2v[4];
        #pragma unroll
        for (int j = 0; j < 4; ++j) x2v[j] = __shfl(a2, 4*g + j);
        #pragma unroll
        for (int kt = 0; kt < 4; ++kt) m2v[kt] = m2g[bb*KK + kt*16 + b];
        float lik[4][4];
        float tot[4] = {0.f, 0.f, 0.f, 0.f};
        #pragma unroll
        for (int kt = 0; kt < 4; ++kt)
            #pragma unroll
            for (int j = 0; j < 4; ++j) {
                float s = acc1[kt][j];
                float L = expf(-0.5f * (x2v[j] - 2.f*s + m2v[kt])) + 1e-20f;
                lik[kt][j] = L;
                tot[j] += L;
            }
        #pragma unroll
        for (int j = 0; j < 4; ++j) {
            tot[j] += __shfl_xor(tot[j], 1);
            tot[j] += __shfl_xor(tot[j], 2);
            tot[j] += __shfl_xor(tot[j], 4);
            tot[j] += __shfl_xor(tot[j], 8);
            tot[j] = 1.f / (tot[j] + 1e-40f);
        }
        // write P transposed (hi/lo): rows k = 16kt + b, cols n = 16w + 4g + j
        int np = 16*w + 4*g;
        #pragma unroll
        for (int kt = 0; kt < 4; ++kt) {
            int k = kt*16 + b;
            ushort4 uh, ul;
            float P0 = lik[kt][0]*tot[0]; uh.x = f2bf(P0); ul.x = f2bf(P0 - bf2f(uh.x));
            float P1 = lik[kt][1]*tot[1]; uh.y = f2bf(P1); ul.y = f2bf(P1 - bf2f(uh.y));
            float P2 = lik[kt][2]*tot[2]; uh.z = f2bf(P2); ul.z = f2bf(P2 - bf2f(uh.z));
            float P3 = lik[kt][3]*tot[3]; uh.w = f2bf(P3); ul.w = f2bf(P3 - bf2f(uh.w));
            int idx = k*TILE + (((np>>3) ^ (k&7)) << 3) + (np & 7);
            *(ushort4*)(&pTh[idx]) = uh;
            *(ushort4*)(&pTl[idx]) = ul;
        }
    }
    __syncthreads();   // bar2: pT ready

    // ===== GEMM2: mu_out[k][f] += P^T . x  (contract n; 16 waves x 2 f-tiles) =====
    int mt2 = w & 3;
    int fpair = w >> 2;                   // 0..3 -> f-tiles {2*fpair, 2*fpair+1}
    f32x4 c0 = {0.f,0.f,0.f,0.f}, c1 = {0.f,0.f,0.f,0.f};
    int kA = 16*mt2 + b;                  // A-row (cluster k)
    int fB0 = 16*(2*fpair) + b;           // B-cols (f)
    int fB1 = 16*(2*fpair + 1) + b;

    #pragma unroll
    for (int ns = 0; ns < 2; ++ns) {      // n = 0..63
        int gp = 4*ns + g;                // pT granule (global n)
        int gx = 4*ns + g;                // xT granule (local n)
        int ia = kA*TILE + ((gp ^ (kA&7)) << 3);
        bf16x8 Ah = *(const bf16x8*)(&pTh[ia]);
        bf16x8 Al = *(const bf16x8*)(&pTl[ia]);
        int ib0 = fB0*64 + ((gx ^ (fB0&7)) << 3);
        int ib1 = fB1*64 + ((gx ^ (fB1&7)) << 3);
        bf16x8 B0h = *(const bf16x8*)(&xTh[ib0]);
        bf16x8 B0l = *(const bf16x8*)(&xTl[ib0]);
        bf16x8 B1h = *(const bf16x8*)(&xTh[ib1]);
        bf16x8 B1l = *(const bf16x8*)(&xTl[ib1]);
        c0 = __builtin_amdgcn_mfma_f32_16x16x32_bf16(Ah, B0h, c0, 0, 0, 0);
        c0 = __builtin_amdgcn_mfma_f32_16x16x32_bf16(Ah, B0l, c0, 0, 0, 0);
        c0 = __builtin_amdgcn_mfma_f32_16x16x32_bf16(Al, B0h, c0, 0, 0, 0);
        c1 = __builtin_amdgcn_mfma_f32_16x16x32_bf16(Ah, B1h, c1, 0, 0, 0);
        c1 = __builtin_amdgcn_mfma_f32_16x16x32_bf16(Ah, B1l, c1, 0, 0, 0);
        c1 = __builtin_amdgcn_mfma_f32_16x16x32_bf16(Al, B1h, c1, 0, 0, 0);
    }
    __syncthreads();   // bar3: done reading xT half1

    {   // ===== rebuild xT with tile rows 64..127 (all 16 waves) =====
        int nl = t & 63;
        int fq = t >> 6;                  // 0..15
        int gn = row0 + 64 + nl;
        bool valid = gn < nb;
        const float* er = emb + ((size_t)bb * NN + gn) * FF;
        #pragma unroll
        for (int it = 0; it < 2; ++it) {
            int f4 = fq + 16*it;
            float4 e = valid ? *(const float4*)(er + 4*f4) : make_float4(0.f,0.f,0.f,0.f);
            float4 mn = *(const float4*)(mnB + 4*f4);
            float4 rs = *(const float4*)(rsB + 4*f4);
            float vx[4];
            vx[0] = valid ? (e.x - mn.x)*rs.x : 0.f;
            vx[1] = valid ? (e.y - mn.y)*rs.y : 0.f;
            vx[2] = valid ? (e.z - mn.z)*rs.z : 0.f;
            vx[3] = valid ? (e.w - mn.w)*rs.w : 0.f;
            #pragma unroll
            for (int ei = 0; ei < 4; ++ei) {
                int f = 4*f4 + ei;
                ushort h = f2bf(vx[ei]);
                ushort l = f2bf(vx[ei] - bf2f(h));
                int idx = f*64 + ((((nl>>3) ^ (f&7)) << 3) | (nl & 7));
                xTh[idx] = h;
                xTl[idx] = l;
            }
        }
    }
    __syncthreads();   // bar4: xT half2 ready

    #pragma unroll
    for (int ns = 2; ns < 4; ++ns) {      // n = 64..127
        int gp = 4*ns + g;                // pT granule (global n)
        int gx = 4*(ns - 2) + g;          // xT granule (local n)
        int ia = kA*TILE + ((gp ^ (kA&7)) << 3);
        bf16x8 Ah = *(const bf16x8*)(&pTh[ia]);
        bf16x8 Al = *(const bf16x8*)(&pTl[ia]);
        int ib0 = fB0*64 + ((gx ^ (fB0&7)) << 3);
        int ib1 = fB1*64 + ((gx ^ (fB1&7)) << 3);
        bf16x8 B0h = *(const bf16x8*)(&xTh[ib0]);
        bf16x8 B0l = *(const bf16x8*)(&xTl[ib0]);
        bf16x8 B1h = *(const bf16x8*)(&xTh[ib1]);
        bf16x8 B1l = *(const bf16x8*)(&xTl[ib1]);
        c0 = __builtin_amdgcn_mfma_f32_16x16x32_bf16(Ah, B0h, c0, 0, 0, 0);
        c0 = __builtin_amdgcn_mfma_f32_16x16x32_bf16(Ah, B0l, c0, 0, 0, 0);
        c0 = __builtin_amdgcn_mfma_f32_16x16x32_bf16(Al, B0h, c0, 0, 0, 0);
        c1 = __builtin_amdgcn_mfma_f32_16x16x32_bf16(Ah, B1h, c1, 0, 0, 0);
        c1 = __builtin_amdgcn_mfma_f32_16x16x32_bf16(Ah, B1l, c1, 0, 0, 0);
        c1 = __builtin_amdgcn_mfma_f32_16x16x32_bf16(Al, B1h, c1, 0, 0, 0);
    }

    // ===== epilogue: atomic accumulate into mu_out (f32) =====
    {
        float* mo = mu_out + (size_t)bb * KK * FF;
        #pragma unroll
        for (int j = 0; j < 4; ++j) {
            int ko = 16*mt2 + 4*g + j;
            unsafeAtomicAdd(mo + (size_t)ko * FF + fB0, c0[j]);
            unsafeAtomicAdd(mo + (size_t)ko * FF + fB1, c1[j]);
        }
    }
}

// ---------- final: out[b] = sigmoid(mean_k(mu . w) + bias) ----------
__global__ void k_final(const float* __restrict__ mu, const float* __restrict__ fc_w,
                        const float* __restrict__ fc_b, float* __restrict__ out) {
    int b = blockIdx.x, t = threadIdx.x;     // 256 threads
    int k = t >> 2, q = t & 3;
    const float* m = mu + ((size_t)b * KK + k) * FF + q * 32;
    const float* wv = fc_w + q * 32;
    float s = 0.f;
    #pragma unroll
    for (int i = 0; i < 32; ++i) s = fmaf(m[i], wv[i], s);
    s += __shfl_xor(s, 1); s += __shfl_xor(s, 2);
    __shared__ float kd[KK];
    if (q == 0) kd[k] = s;
    __syncthreads();
    if (t < 64) {
        float v = kd[t];
        v += __shfl_xor(v, 1);  v += __shfl_xor(v, 2);  v += __shfl_xor(v, 4);
        v += __shfl_xor(v, 8);  v += __shfl_xor(v, 16); v += __shfl_xor(v, 32);
        if (t == 0) {
            float o = v / (float)KK + fc_b[0];
            out[b] = 1.f / (1.f + expf(-o));
        }
    }
}

extern "C" void kernel_launch(void* const* d_in, const int* in_sizes, int n_in,
                              void* d_out, int out_size, void* d_ws, size_t ws_size,
                              hipStream_t stream) {
    const float* emb      = (const float*)d_in[0];
    // d_in[1] = mask — redundant with batch_nb_nodes; unused
    const float* fc_w     = (const float*)d_in[2];
    const float* fc_b     = (const float*)d_in[3];
    const int*   nbv      = (const int*)d_in[4];
    const int*   init_idx = (const int*)d_in[5];
    float* out = (float*)d_out;

    float* wsf   = (float*)d_ws;
    float* meanp = wsf;                                // B*F
    float* rstdp = meanp + BB*FF;                      // B*F
    float* spart = rstdp + BB*FF;                      // B*SPB*2*F = 524288
    float* muA   = spart + (size_t)BB*SPB*2*FF;        // B*K*F f32
    float* muB   = muA + (size_t)BB*KK*FF;             // B*K*F f32
    float* m2g   = muB + (size_t)BB*KK*FF;             // B*K
    ushort* muh  = (ushort*)(m2g + BB*KK);             // B*K*F bf16
    ushort* mul  = muh + (size_t)BB*KK*FF;             // B*K*F bf16

    k_stats_part<<<dim3(SPB, BB), 256, 0, stream>>>(emb, nbv, spart);
    k_stats_fin<<<BB, 128, 0, stream>>>(spart, nbv, meanp, rstdp);
    k_init<<<(BB*KK*FF)/256, 256, 0, stream>>>(emb, nbv, init_idx, meanp, rstdp, muA);

    const int zblocks = (BB*KK*FF/4) / 256;            // 512
    for (int step = 0; step < NSTEP; ++step) {
        const float* mu_in = (step & 1) ? muB : muA;
        float* mu_out      = (step & 1) ? muA : muB;
        k_split<<<BB, 256, 0, stream>>>(mu_in, muh, mul, m2g);
        k_zero<<<zblocks, 256, 0, stream>>>(mu_out);
        k_em3<<<dim3(NN/TILE, BB), 1024, 0, stream>>>(emb, nbv, meanp, rstdp,
                                                      muh, mul, m2g, mu_out);
    }
    // after step 3, result is in muA
    k_final<<<BB, 256, 0, stream>>>(muA, fc_w, fc_b, out);
}